// Round 1
// baseline (325.681 us; speedup 1.0000x reference)
//
#include <hip/hip_runtime.h>

#define NN 50000
#define NP 50176        // padded node stride (multiple of 256)
#define TT 518
#define KC 32
#define LL 163
#define HH 128
#define EE 1600000
#define NB 196          // node blocks: 196*256 = 50176 >= NN
#define NCOPY 8

// ---- chunked-LDS scatter (no global atomics) ----
#define CKN 4           // node chunks
#define CSZ 12544       // nodes/chunk (4*12544 = 50176), LDS acc = 50176 B
#define PSL 128         // edge slices (partials per chunk)
#define GSC (CKN*PSL)   // 512 blocks
#define ESL (EE/PSL)    // 12500 edges per slice (divisible by 4)

// ---- conv2: LDS-staged full-L conv ----
#define CN 16           // nodes per conv block (NN = 3125*16 exactly)
#define NB3 3125        // conv grid
#define LPG 11          // l's per lane-group (16 groups * 11 = 176 >= 163)
#define TPT 62          // t-extent per thread = 3*LPG + 29
#define VS 16           // v accumulator stripes
#define VSTR 192        // stripe stride (>= LL, 16B-aligned)

// deg partials: block (chunk=b&3, p=b>>2) scans slice p, bins col hits into
// LDS, flushes private partial with plain stores. R4 evidence: 1.6M global
// atomics cost 32B fabric transactions each (WRITE_SIZE 49.8MB) — LDS
// privatization removes them entirely.
__global__ __launch_bounds__(256) void k_deg_part(const int* __restrict__ col,
                                                  const float* __restrict__ ea,
                                                  float* __restrict__ part) {
  __shared__ float acc[CSZ];
  int tid = threadIdx.x;
  for (int j = tid; j < CSZ; j += 256) acc[j] = 0.f;
  __syncthreads();
  int chunk = blockIdx.x & (CKN - 1);
  int base = chunk * CSZ;
  const int4*   c4p = (const int4*)col + (blockIdx.x >> 2) * (ESL / 4);
  const float4* a4p = (const float4*)ea + (blockIdx.x >> 2) * (ESL / 4);
  for (int i = tid; i < ESL / 4; i += 256) {
    int4   c4 = c4p[i];
    float4 a4 = a4p[i];
    unsigned jx = (unsigned)(c4.x - base);
    unsigned jy = (unsigned)(c4.y - base);
    unsigned jz = (unsigned)(c4.z - base);
    unsigned jw = (unsigned)(c4.w - base);
    if (jx < CSZ) atomicAdd(&acc[jx], a4.x);
    if (jy < CSZ) atomicAdd(&acc[jy], a4.y);
    if (jz < CSZ) atomicAdd(&acc[jz], a4.z);
    if (jw < CSZ) atomicAdd(&acc[jw], a4.w);
  }
  __syncthreads();
  float* out = part + (size_t)blockIdx.x * CSZ;
  for (int j = tid; j < CSZ; j += 256) out[j] = acc[j];
}

// dinv[i] = rsqrt(1 + sum_p degpart[p][i])
__global__ __launch_bounds__(256) void k_dinv2(const float* __restrict__ part,
                                               float* __restrict__ dinv) {
  int i = blockIdx.x * 256 + threadIdx.x;
  if (i >= NN) return;
  int chunk = i / CSZ, j = i - chunk * CSZ;
  const float* q = part + (size_t)chunk * CSZ + j;
  float s = 1.0f;
#pragma unroll 8
  for (int p = 0; p < PSL; ++p) s += q[(size_t)p * (CKN * CSZ)];
  dinv[i] = rsqrtf(s);
}

// coef partials: acc[row] += ea * dinv[col].  The dinv[row] factor is
// constant per slot -> folded into k_csum2, eliminating 1.6M row-gathers.
__global__ __launch_bounds__(256) void k_coef_part(const int* __restrict__ row,
                                                   const int* __restrict__ col,
                                                   const float* __restrict__ ea,
                                                   const float* __restrict__ dinv,
                                                   float* __restrict__ part) {
  __shared__ float acc[CSZ];
  int tid = threadIdx.x;
  for (int j = tid; j < CSZ; j += 256) acc[j] = 0.f;
  __syncthreads();
  int chunk = blockIdx.x & (CKN - 1);
  int base = chunk * CSZ;
  const int4*   r4p = (const int4*)row + (blockIdx.x >> 2) * (ESL / 4);
  const int4*   c4p = (const int4*)col + (blockIdx.x >> 2) * (ESL / 4);
  const float4* a4p = (const float4*)ea + (blockIdx.x >> 2) * (ESL / 4);
  for (int i = tid; i < ESL / 4; i += 256) {
    int4   r4 = r4p[i];
    int4   c4 = c4p[i];
    float4 a4 = a4p[i];
    unsigned jx = (unsigned)(r4.x - base);
    unsigned jy = (unsigned)(r4.y - base);
    unsigned jz = (unsigned)(r4.z - base);
    unsigned jw = (unsigned)(r4.w - base);
    if (jx < CSZ) atomicAdd(&acc[jx], a4.x * dinv[c4.x]);
    if (jy < CSZ) atomicAdd(&acc[jy], a4.y * dinv[c4.y]);
    if (jz < CSZ) atomicAdd(&acc[jz], a4.z * dinv[c4.z]);
    if (jw < CSZ) atomicAdd(&acc[jw], a4.w * dinv[c4.w]);
  }
  __syncthreads();
  float* out = part + (size_t)blockIdx.x * CSZ;
  for (int j = tid; j < CSZ; j += 256) out[j] = acc[j];
}

// c[i] = dinv[i]^2 + dinv[i] * sum_p coefpart[p][i]
__global__ __launch_bounds__(256) void k_csum2(const float* __restrict__ part,
                                               const float* __restrict__ dinv,
                                               float* __restrict__ c) {
  int i = blockIdx.x * 256 + threadIdx.x;
  if (i >= NN) return;
  int chunk = i / CSZ, j = i - chunk * CSZ;
  const float* q = part + (size_t)chunk * CSZ + j;
  float s = 0.0f;
#pragma unroll 8
  for (int p = 0; p < PSL; ++p) s += q[(size_t)p * (CKN * CSZ)];
  float di = dinv[i];
  c[i] = di * di + di * s;
}

// ---- fallback path (R4 global-atomic version) if ws is too small ----
__global__ __launch_bounds__(256) void k_deg(const int* __restrict__ col,
                                             const float* __restrict__ ea,
                                             float* __restrict__ deg8) {
  int i = blockIdx.x * 256 + threadIdx.x;
  float* d = deg8 + (blockIdx.x & 7) * NP;
  if (i < EE / 4) {
    int4   c4 = ((const int4*)col)[i];
    float4 a4 = ((const float4*)ea)[i];
    atomicAdd(&d[c4.x], a4.x);
    atomicAdd(&d[c4.y], a4.y);
    atomicAdd(&d[c4.z], a4.z);
    atomicAdd(&d[c4.w], a4.w);
  }
}
__global__ __launch_bounds__(256) void k_dinv(const float* __restrict__ deg8,
                                              float* __restrict__ dinv) {
  int i = blockIdx.x * 256 + threadIdx.x;
  if (i < NN) {
    float s = 1.0f;
#pragma unroll
    for (int j = 0; j < NCOPY; ++j) s += deg8[j * NP + i];
    dinv[i] = rsqrtf(s);
  }
}
__global__ __launch_bounds__(256) void k_coef(const int* __restrict__ row,
                                              const int* __restrict__ col,
                                              const float* __restrict__ ea,
                                              const float* __restrict__ dinv,
                                              float* __restrict__ coef8) {
  int i = blockIdx.x * 256 + threadIdx.x;
  float* cf = coef8 + (blockIdx.x & 7) * NP;
  if (i < EE / 4) {
    int4   r4 = ((const int4*)row)[i];
    int4   c4 = ((const int4*)col)[i];
    float4 a4 = ((const float4*)ea)[i];
    atomicAdd(&cf[r4.x], a4.x * dinv[c4.x] * dinv[r4.x]);
    atomicAdd(&cf[r4.y], a4.y * dinv[c4.y] * dinv[r4.y]);
    atomicAdd(&cf[r4.z], a4.z * dinv[c4.z] * dinv[r4.z]);
    atomicAdd(&cf[r4.w], a4.w * dinv[c4.w] * dinv[r4.w]);
  }
}
__global__ __launch_bounds__(256) void k_csum(const float* __restrict__ coef8,
                                              const float* __restrict__ dinv,
                                              float* __restrict__ c) {
  int i = blockIdx.x * 256 + threadIdx.x;
  if (i < NN) {
    float di = dinv[i];
    float s = di * di;
#pragma unroll
    for (int j = 0; j < NCOPY; ++j) s += coef8[j * NP + i];
    c[i] = s;
  }
}

// v[l] += sum_n c[n]*relu(conv(x,w)+b)[l], computed with x staged in LDS so
// x is read from global EXACTLY ONCE (103.6 MB total; old version re-read
// overlapping windows 21x = 223 MB and conv weights 21x = 134 MB).
// Block = 16 nodes (full 518-t stripe in LDS, 33 KB -> 4 blocks/CU).
// Thread (n = tid&15, g = tid>>4): computes l in [11g, 11g+11) for node n
// via a t-major sweep: acc[u] += x_t * w[t-3u]; all indices compile-time
// after full unroll (no scratch).  LDS reads: addr = t*16+n -> 64 lanes =
// 4 t-groups x 16 consecutive n = 2 lanes/bank (free).
__global__ __launch_bounds__(256, 4) void k_conv2(const float* __restrict__ x,
                                                  const float* __restrict__ cw,
                                                  const float* __restrict__ cb,
                                                  const float* __restrict__ c,
                                                  float* __restrict__ v16) {
  __shared__ __align__(16) float xs[TT * CN];   // 518*16*4 = 33 KB
  int tid = threadIdx.x;
  int n0 = blockIdx.x * CN;
  // stage x[0..517][n0..n0+15] -> xs; 2072 float4 slots, coalesced
  for (int f = tid; f < TT * (CN / 4); f += 256) {
    int r = f >> 2, q = f & 3;
    int col = n0 + q * 4;                 // NN%16==0 -> never OOB, kept safe
    if (col > NN - 4) col = NN - 4;
    ((float4*)xs)[f] = *(const float4*)(x + (size_t)r * NN + col);
  }
  int n = tid & (CN - 1), g = tid >> 4;   // g in 0..15 (g=15 fully discarded)
  int nn = n0 + n;
  int nc = nn < NN ? nn : NN - 1;
  float cn = nn < NN ? c[nn] : 0.f;
  float bn = cb[nc];
  float w[KC];
  const float4* w4 = (const float4*)(cw + (size_t)nc * KC);
#pragma unroll
  for (int k = 0; k < KC / 4; ++k) {
    float4 t = w4[k];
    w[4 * k] = t.x; w[4 * k + 1] = t.y; w[4 * k + 2] = t.z; w[4 * k + 3] = t.w;
  }
  __syncthreads();

  int t0 = 3 * LPG * g;                   // 33*g
  float acc[LPG];
#pragma unroll
  for (int u = 0; u < LPG; ++u) acc[u] = 0.f;
#pragma unroll
  for (int tr = 0; tr < TPT; ++tr) {
    int ta = t0 + tr;
    ta = ta < TT ? ta : TT - 1;           // clamp only pollutes discarded u's
    float xt = xs[ta * CN + n];
    const int ulo = (tr > 31) ? (tr - 29) / 3 : 0;        // ceil((tr-31)/3)
    const int uhi = (tr / 3 < LPG - 1) ? tr / 3 : LPG - 1;
#pragma unroll
    for (int u = ulo; u <= uhi; ++u) acc[u] += xt * w[tr - 3 * u];
  }

  // relu + scale by c[n], reduce over the 16 node-lanes, flush to stripe
  float* vdst = v16 + (blockIdx.x & (VS - 1)) * VSTR;
#pragma unroll
  for (int u = 0; u < LPG; ++u) {
    float hv = acc[u] + bn;
    hv = hv > 0.f ? hv : 0.f;
    float val = cn * hv;
    val += __shfl_xor(val, 1, 64);
    val += __shfl_xor(val, 2, 64);
    val += __shfl_xor(val, 4, 64);
    val += __shfl_xor(val, 8, 64);
    int l = LPG * g + u;
    if (n == 0 && l < LL) atomicAdd(&vdst[l], val);
  }
}

// out[h] = (sum_l (sum_j v16[j][l]) * W[l][h]) / N + gcn_b[h]
__global__ __launch_bounds__(128) void k_out(const float* __restrict__ v16,
                                             const float* __restrict__ W,
                                             const float* __restrict__ b,
                                             float* __restrict__ out) {
  __shared__ float vs[LL];
  int h = threadIdx.x;
  for (int l = h; l < LL; l += 128) {
    float s = 0.f;
#pragma unroll
    for (int j = 0; j < VS; ++j) s += v16[j * VSTR + l];
    vs[l] = s;
  }
  __syncthreads();
  float s = 0.f;
  for (int l = 0; l < LL; ++l) s += vs[l] * W[l * HH + h];
  out[h] = s * (1.0f / NN) + b[h];
}

extern "C" void kernel_launch(void* const* d_in, const int* in_sizes, int n_in,
                              void* d_out, int out_size, void* d_ws, size_t ws_size,
                              hipStream_t stream) {
  const float* x  = (const float*)d_in[0];
  const int*   ei = (const int*)d_in[1];
  const float* ea = (const float*)d_in[2];
  const float* cw = (const float*)d_in[3];
  const float* cb = (const float*)d_in[4];
  const float* gW = (const float*)d_in[5];
  const float* gb = (const float*)d_in[6];
  float* out = (float*)d_out;

  const int* row = ei;
  const int* col = ei + EE;
  float* ws = (float*)d_ws;

  size_t need_new = ((size_t)GSC * CSZ + VS * VSTR + 2 * NP) * sizeof(float);
  if (ws_size >= need_new) {
    float* part = ws;                          // GSC*CSZ floats (reused deg->coef)
    float* v16  = ws + (size_t)GSC * CSZ;      // VS*VSTR floats
    float* dinv = v16 + VS * VSTR;             // NP floats
    float* c    = dinv + NP;                   // NP floats
    hipMemsetAsync(v16, 0, VS * VSTR * sizeof(float), stream);
    k_deg_part <<<GSC, 256, 0, stream>>>(col, ea, part);
    k_dinv2    <<<NB, 256, 0, stream>>>(part, dinv);
    k_coef_part<<<GSC, 256, 0, stream>>>(row, col, ea, dinv, part);
    k_csum2    <<<NB, 256, 0, stream>>>(part, dinv, c);
    k_conv2    <<<NB3, 256, 0, stream>>>(x, cw, cb, c, v16);
    k_out      <<<1, 128, 0, stream>>>(v16, gW, gb, out);
  } else {
    float* deg8  = ws;
    float* coef8 = ws + NCOPY * NP;
    float* v16   = ws + 2 * NCOPY * NP;
    float* dinv  = ws + 2 * NCOPY * NP + VS * VSTR;
    float* c     = dinv + NP;
    hipMemsetAsync(deg8, 0, (2 * NCOPY * NP + VS * VSTR) * sizeof(float), stream);
    int egrid = (EE / 4 + 255) / 256;
    k_deg  <<<egrid, 256, 0, stream>>>(col, ea, deg8);
    k_dinv <<<NB, 256, 0, stream>>>(deg8, dinv);
    k_coef <<<egrid, 256, 0, stream>>>(row, col, ea, dinv, coef8);
    k_csum <<<NB, 256, 0, stream>>>(coef8, dinv, c);
    k_conv2<<<NB3, 256, 0, stream>>>(x, cw, cb, c, v16);
    k_out  <<<1, 128, 0, stream>>>(v16, gW, gb, out);
  }
}

// Round 2
// 303.146 us; speedup vs baseline: 1.0743x; 1.0743x over previous
//
#include <hip/hip_runtime.h>

#define NN 50000
#define NP 50176        // padded node stride (multiple of 256)
#define TT 518
#define KC 32
#define LL 163
#define HH 128
#define EE 1600000
#define NB 196          // node blocks: 196*256 = 50176 >= NN
#define NCOPY 8

// ---- chunked-LDS scatter (no global atomics) ----
#define CKN 4           // node chunks
#define CSZ 12544       // nodes/chunk (4*12544 = 50176), LDS acc = 50176 B
#define PSL 128         // edge slices (partials per chunk)
#define GSC (CKN*PSL)   // 512 blocks
#define ESL (EE/PSL)    // 12500 edges per slice (divisible by 4)

// ---- conv3: register-window full-L conv ----
#define GRP 3           // l-groups per block
#define CPG 7           // l-chunks per group (3*7*8 = 168 >= 163)
#define WIN 197         // register window: 24*(CPG-1) + 3*7 + 32 = 197
#define VS 16           // v accumulator stripes
#define VSTR 192        // stripe stride (>= LL, 16B-aligned)

// deg partials: block (chunk=b&3, p=b>>2) scans slice p, bins col hits into
// LDS, flushes private partial with plain stores. R4 evidence: 1.6M global
// atomics cost 32B fabric transactions each (WRITE_SIZE 49.8MB) — LDS
// privatization removes them entirely.
__global__ __launch_bounds__(256) void k_deg_part(const int* __restrict__ col,
                                                  const float* __restrict__ ea,
                                                  float* __restrict__ part) {
  __shared__ float acc[CSZ];
  int tid = threadIdx.x;
  for (int j = tid; j < CSZ; j += 256) acc[j] = 0.f;
  __syncthreads();
  int chunk = blockIdx.x & (CKN - 1);
  int base = chunk * CSZ;
  const int4*   c4p = (const int4*)col + (blockIdx.x >> 2) * (ESL / 4);
  const float4* a4p = (const float4*)ea + (blockIdx.x >> 2) * (ESL / 4);
  for (int i = tid; i < ESL / 4; i += 256) {
    int4   c4 = c4p[i];
    float4 a4 = a4p[i];
    unsigned jx = (unsigned)(c4.x - base);
    unsigned jy = (unsigned)(c4.y - base);
    unsigned jz = (unsigned)(c4.z - base);
    unsigned jw = (unsigned)(c4.w - base);
    if (jx < CSZ) atomicAdd(&acc[jx], a4.x);
    if (jy < CSZ) atomicAdd(&acc[jy], a4.y);
    if (jz < CSZ) atomicAdd(&acc[jz], a4.z);
    if (jw < CSZ) atomicAdd(&acc[jw], a4.w);
  }
  __syncthreads();
  float* out = part + (size_t)blockIdx.x * CSZ;
  for (int j = tid; j < CSZ; j += 256) out[j] = acc[j];
}

// dinv[i] = rsqrt(1 + sum_p degpart[p][i])
__global__ __launch_bounds__(256) void k_dinv2(const float* __restrict__ part,
                                               float* __restrict__ dinv) {
  int i = blockIdx.x * 256 + threadIdx.x;
  if (i >= NN) return;
  int chunk = i / CSZ, j = i - chunk * CSZ;
  const float* q = part + (size_t)chunk * CSZ + j;
  float s = 1.0f;
#pragma unroll 8
  for (int p = 0; p < PSL; ++p) s += q[(size_t)p * (CKN * CSZ)];
  dinv[i] = rsqrtf(s);
}

// coef partials: acc[row] += ea * dinv[col].  The dinv[row] factor is
// constant per slot -> folded into k_csum2, eliminating 1.6M row-gathers.
__global__ __launch_bounds__(256) void k_coef_part(const int* __restrict__ row,
                                                   const int* __restrict__ col,
                                                   const float* __restrict__ ea,
                                                   const float* __restrict__ dinv,
                                                   float* __restrict__ part) {
  __shared__ float acc[CSZ];
  int tid = threadIdx.x;
  for (int j = tid; j < CSZ; j += 256) acc[j] = 0.f;
  __syncthreads();
  int chunk = blockIdx.x & (CKN - 1);
  int base = chunk * CSZ;
  const int4*   r4p = (const int4*)row + (blockIdx.x >> 2) * (ESL / 4);
  const int4*   c4p = (const int4*)col + (blockIdx.x >> 2) * (ESL / 4);
  const float4* a4p = (const float4*)ea + (blockIdx.x >> 2) * (ESL / 4);
  for (int i = tid; i < ESL / 4; i += 256) {
    int4   r4 = r4p[i];
    int4   c4 = c4p[i];
    float4 a4 = a4p[i];
    unsigned jx = (unsigned)(r4.x - base);
    unsigned jy = (unsigned)(r4.y - base);
    unsigned jz = (unsigned)(r4.z - base);
    unsigned jw = (unsigned)(r4.w - base);
    if (jx < CSZ) atomicAdd(&acc[jx], a4.x * dinv[c4.x]);
    if (jy < CSZ) atomicAdd(&acc[jy], a4.y * dinv[c4.y]);
    if (jz < CSZ) atomicAdd(&acc[jz], a4.z * dinv[c4.z]);
    if (jw < CSZ) atomicAdd(&acc[jw], a4.w * dinv[c4.w]);
  }
  __syncthreads();
  float* out = part + (size_t)blockIdx.x * CSZ;
  for (int j = tid; j < CSZ; j += 256) out[j] = acc[j];
}

// c[i] = dinv[i]^2 + dinv[i] * sum_p coefpart[p][i]
__global__ __launch_bounds__(256) void k_csum2(const float* __restrict__ part,
                                               const float* __restrict__ dinv,
                                               float* __restrict__ c) {
  int i = blockIdx.x * 256 + threadIdx.x;
  if (i >= NN) return;
  int chunk = i / CSZ, j = i - chunk * CSZ;
  const float* q = part + (size_t)chunk * CSZ + j;
  float s = 0.0f;
#pragma unroll 8
  for (int p = 0; p < PSL; ++p) s += q[(size_t)p * (CKN * CSZ)];
  float di = dinv[i];
  c[i] = di * di + di * s;
}

// ---- fallback path (R4 global-atomic version) if ws is too small ----
__global__ __launch_bounds__(256) void k_deg(const int* __restrict__ col,
                                             const float* __restrict__ ea,
                                             float* __restrict__ deg8) {
  int i = blockIdx.x * 256 + threadIdx.x;
  float* d = deg8 + (blockIdx.x & 7) * NP;
  if (i < EE / 4) {
    int4   c4 = ((const int4*)col)[i];
    float4 a4 = ((const float4*)ea)[i];
    atomicAdd(&d[c4.x], a4.x);
    atomicAdd(&d[c4.y], a4.y);
    atomicAdd(&d[c4.z], a4.z);
    atomicAdd(&d[c4.w], a4.w);
  }
}
__global__ __launch_bounds__(256) void k_dinv(const float* __restrict__ deg8,
                                              float* __restrict__ dinv) {
  int i = blockIdx.x * 256 + threadIdx.x;
  if (i < NN) {
    float s = 1.0f;
#pragma unroll
    for (int j = 0; j < NCOPY; ++j) s += deg8[j * NP + i];
    dinv[i] = rsqrtf(s);
  }
}
__global__ __launch_bounds__(256) void k_coef(const int* __restrict__ row,
                                              const int* __restrict__ col,
                                              const float* __restrict__ ea,
                                              const float* __restrict__ dinv,
                                              float* __restrict__ coef8) {
  int i = blockIdx.x * 256 + threadIdx.x;
  float* cf = coef8 + (blockIdx.x & 7) * NP;
  if (i < EE / 4) {
    int4   r4 = ((const int4*)row)[i];
    int4   c4 = ((const int4*)col)[i];
    float4 a4 = ((const float4*)ea)[i];
    atomicAdd(&cf[r4.x], a4.x * dinv[c4.x] * dinv[r4.x]);
    atomicAdd(&cf[r4.y], a4.y * dinv[c4.y] * dinv[r4.y]);
    atomicAdd(&cf[r4.z], a4.z * dinv[c4.z] * dinv[r4.z]);
    atomicAdd(&cf[r4.w], a4.w * dinv[c4.w] * dinv[r4.w]);
  }
}
__global__ __launch_bounds__(256) void k_csum(const float* __restrict__ coef8,
                                              const float* __restrict__ dinv,
                                              float* __restrict__ c) {
  int i = blockIdx.x * 256 + threadIdx.x;
  if (i < NN) {
    float di = dinv[i];
    float s = di * di;
#pragma unroll
    for (int j = 0; j < NCOPY; ++j) s += coef8[j * NP + i];
    c[i] = s;
  }
}

// v[l] += sum_n c[n]*relu(conv(x,w)+b)[l].
// conv3: thread = node (old k_conv's proven 256B/wave streaming granule,
// measured ~5.2 TB/s), but ONE block does ALL 163 l's for its 256 nodes:
//   - w loaded once (old: 21x = 134 MB extra)
//   - x loaded 1.14x via 3 groups of 7 l-chunks sharing a 197-float
//     register window, all indices compile-time (old: 2.15x)
// Traffic: 118.6 MB x + 6.4 MB w ~= 125 MB @ ~5 TB/s -> ~24 us predicted.
// VGPR ~250 expected -> launch_bounds(256,1); 784 waves = 1/SIMD is fine
// because each wave keeps ~60 independent loads in flight (BW-bound).
__global__ __launch_bounds__(256, 1) void k_conv3(const float* __restrict__ x,
                                                  const float* __restrict__ cw,
                                                  const float* __restrict__ cb,
                                                  const float* __restrict__ c,
                                                  float* __restrict__ v16) {
  __shared__ float vloc[LL];
  int tid = threadIdx.x;
  for (int j = tid; j < LL; j += 256) vloc[j] = 0.f;
  __syncthreads();

  int n = blockIdx.x * 256 + tid;
  int nc = n < NN ? n : NN - 1;    // clamp for safe loads; cn=0 kills contrib
  float cn = n < NN ? c[n] : 0.f;
  float bn = cb[nc];

  float w[KC];
  const float4* w4 = (const float4*)(cw + (size_t)nc * KC);
#pragma unroll
  for (int k = 0; k < KC / 4; ++k) {
    float4 t = w4[k];
    w[4 * k] = t.x; w[4 * k + 1] = t.y; w[4 * k + 2] = t.z; w[4 * k + 3] = t.w;
  }
  const float* xp = x + nc;
  int lane = tid & 63;

#pragma unroll 1
  for (int g = 0; g < GRP; ++g) {
    // load register window: t in [168g, 168g+197), clamped (pollutes only
    // discarded l's: valid l<=162 needs t<=517, and j>=182 only feeds l>=163)
    float xs[WIN];
#pragma unroll
    for (int j = 0; j < WIN; ++j) {
      int t = 168 * g + j;
      t = t < TT ? t : TT - 1;
      xs[j] = xp[(size_t)t * NN];
    }
#pragma unroll
    for (int cc = 0; cc < CPG; ++cc) {
      float accv[8];
#pragma unroll
      for (int u = 0; u < 8; ++u) {
        float h = 0.f;
#pragma unroll
        for (int k = 0; k < KC; ++k) h += xs[24 * cc + 3 * u + k] * w[k];
        h += bn;
        h = h > 0.f ? h : 0.f;
        accv[u] = cn * h;
      }
#pragma unroll
      for (int u = 0; u < 8; ++u) {
        float val = accv[u];
        val += __shfl_xor(val, 1, 64);
        val += __shfl_xor(val, 2, 64);
        val += __shfl_xor(val, 4, 64);
        val += __shfl_xor(val, 8, 64);
        val += __shfl_xor(val, 16, 64);
        val += __shfl_xor(val, 32, 64);
        int l = 56 * g + 8 * cc + u;     // uniform per wave
        if (lane == 0 && l < LL) atomicAdd(&vloc[l], val);
      }
    }
  }
  __syncthreads();
  float* vdst = v16 + (blockIdx.x & (VS - 1)) * VSTR;
  for (int j = tid; j < LL; j += 256) atomicAdd(&vdst[j], vloc[j]);
}

// out[h] = (sum_l (sum_j v16[j][l]) * W[l][h]) / N + gcn_b[h]
__global__ __launch_bounds__(128) void k_out(const float* __restrict__ v16,
                                             const float* __restrict__ W,
                                             const float* __restrict__ b,
                                             float* __restrict__ out) {
  __shared__ float vs[LL];
  int h = threadIdx.x;
  for (int l = h; l < LL; l += 128) {
    float s = 0.f;
#pragma unroll
    for (int j = 0; j < VS; ++j) s += v16[j * VSTR + l];
    vs[l] = s;
  }
  __syncthreads();
  float s = 0.f;
  for (int l = 0; l < LL; ++l) s += vs[l] * W[l * HH + h];
  out[h] = s * (1.0f / NN) + b[h];
}

extern "C" void kernel_launch(void* const* d_in, const int* in_sizes, int n_in,
                              void* d_out, int out_size, void* d_ws, size_t ws_size,
                              hipStream_t stream) {
  const float* x  = (const float*)d_in[0];
  const int*   ei = (const int*)d_in[1];
  const float* ea = (const float*)d_in[2];
  const float* cw = (const float*)d_in[3];
  const float* cb = (const float*)d_in[4];
  const float* gW = (const float*)d_in[5];
  const float* gb = (const float*)d_in[6];
  float* out = (float*)d_out;

  const int* row = ei;
  const int* col = ei + EE;
  float* ws = (float*)d_ws;

  size_t need_new = ((size_t)GSC * CSZ + VS * VSTR + 2 * NP) * sizeof(float);
  if (ws_size >= need_new) {
    float* part = ws;                          // GSC*CSZ floats (reused deg->coef)
    float* v16  = ws + (size_t)GSC * CSZ;      // VS*VSTR floats
    float* dinv = v16 + VS * VSTR;             // NP floats
    float* c    = dinv + NP;                   // NP floats
    hipMemsetAsync(v16, 0, VS * VSTR * sizeof(float), stream);
    k_deg_part <<<GSC, 256, 0, stream>>>(col, ea, part);
    k_dinv2    <<<NB, 256, 0, stream>>>(part, dinv);
    k_coef_part<<<GSC, 256, 0, stream>>>(row, col, ea, dinv, part);
    k_csum2    <<<NB, 256, 0, stream>>>(part, dinv, c);
    k_conv3    <<<NB, 256, 0, stream>>>(x, cw, cb, c, v16);
    k_out      <<<1, 128, 0, stream>>>(v16, gW, gb, out);
  } else {
    float* deg8  = ws;
    float* coef8 = ws + NCOPY * NP;
    float* v16   = ws + 2 * NCOPY * NP;
    float* dinv  = ws + 2 * NCOPY * NP + VS * VSTR;
    float* c     = dinv + NP;
    hipMemsetAsync(deg8, 0, (2 * NCOPY * NP + VS * VSTR) * sizeof(float), stream);
    int egrid = (EE / 4 + 255) / 256;
    k_deg  <<<egrid, 256, 0, stream>>>(col, ea, deg8);
    k_dinv <<<NB, 256, 0, stream>>>(deg8, dinv);
    k_coef <<<egrid, 256, 0, stream>>>(row, col, ea, dinv, coef8);
    k_csum <<<NB, 256, 0, stream>>>(coef8, dinv, c);
    k_conv3<<<NB, 256, 0, stream>>>(x, cw, cb, c, v16);
    k_out  <<<1, 128, 0, stream>>>(v16, gW, gb, out);
  }
}

// Round 3
// 274.180 us; speedup vs baseline: 1.1878x; 1.1056x over previous
//
#include <hip/hip_runtime.h>

#define NN 50000
#define NP 50176        // padded node stride (multiple of 256)
#define TT 518
#define KC 32
#define LL 163
#define HH 128
#define EE 1600000
#define NB 196          // node blocks: 196*256 = 50176 >= NN
#define NCOPY 8

// ---- chunked-LDS scatter (no global atomics) ----
#define CKN 4           // node chunks
#define CSZ 12544       // nodes/chunk (4*12544 = 50176), LDS acc = 50176 B
#define PSL 64          // edge slices (partials per chunk); 64 -> part = 12.8MB
#define GSC (CKN*PSL)   // 256 blocks = 1/CU
#define ESL (EE/PSL)    // 25000 edges per slice (divisible by 4)

// ---- conv4: l-split register-window conv ----
#define GRP 7           // l-groups, one block each: grid = NB*GRP = 1372
#define LPB 24          // l's per block (7*24 = 168 >= 163)
#define WIN 101         // window: 3*23 + 32 = 101 floats (fits ~150 VGPR)
#define VS 16           // v accumulator stripes
#define VSTR 192        // stripe stride (>= LL, 16B-aligned)

// deg partials: block (chunk=b&3, p=b>>2) scans slice p, bins col hits into
// LDS, flushes private partial with plain stores.
__global__ __launch_bounds__(256) void k_deg_part(const int* __restrict__ col,
                                                  const float* __restrict__ ea,
                                                  float* __restrict__ part) {
  __shared__ float acc[CSZ];
  int tid = threadIdx.x;
  for (int j = tid; j < CSZ; j += 256) acc[j] = 0.f;
  __syncthreads();
  int chunk = blockIdx.x & (CKN - 1);
  int base = chunk * CSZ;
  const int4*   c4p = (const int4*)col + (blockIdx.x >> 2) * (ESL / 4);
  const float4* a4p = (const float4*)ea + (blockIdx.x >> 2) * (ESL / 4);
  for (int i = tid; i < ESL / 4; i += 256) {
    int4   c4 = c4p[i];
    float4 a4 = a4p[i];
    unsigned jx = (unsigned)(c4.x - base);
    unsigned jy = (unsigned)(c4.y - base);
    unsigned jz = (unsigned)(c4.z - base);
    unsigned jw = (unsigned)(c4.w - base);
    if (jx < CSZ) atomicAdd(&acc[jx], a4.x);
    if (jy < CSZ) atomicAdd(&acc[jy], a4.y);
    if (jz < CSZ) atomicAdd(&acc[jz], a4.z);
    if (jw < CSZ) atomicAdd(&acc[jw], a4.w);
  }
  __syncthreads();
  float* out = part + (size_t)blockIdx.x * CSZ;
  for (int j = tid; j < CSZ; j += 256) out[j] = acc[j];
}

// dinv[i] = rsqrt(1 + sum_p degpart[p][i]); 4 accumulators break the serial
// add chain (these kernels run at <1 wave/SIMD -> ILP is the only latency cover)
__global__ __launch_bounds__(256) void k_dinv2(const float* __restrict__ part,
                                               float* __restrict__ dinv) {
  int i = blockIdx.x * 256 + threadIdx.x;
  if (i >= NN) return;
  int chunk = i / CSZ, j = i - chunk * CSZ;
  const float* q = part + (size_t)chunk * CSZ + j;
  float s0 = 0.f, s1 = 0.f, s2 = 0.f, s3 = 0.f;
#pragma unroll
  for (int p = 0; p < PSL; p += 4) {
    s0 += q[(size_t)(p + 0) * (CKN * CSZ)];
    s1 += q[(size_t)(p + 1) * (CKN * CSZ)];
    s2 += q[(size_t)(p + 2) * (CKN * CSZ)];
    s3 += q[(size_t)(p + 3) * (CKN * CSZ)];
  }
  dinv[i] = rsqrtf(1.0f + (s0 + s1) + (s2 + s3));
}

// coef partials: acc[row] += ea * dinv[col].  The dinv[row] factor is
// constant per slot -> folded into k_csum2, eliminating 1.6M row-gathers.
__global__ __launch_bounds__(256) void k_coef_part(const int* __restrict__ row,
                                                   const int* __restrict__ col,
                                                   const float* __restrict__ ea,
                                                   const float* __restrict__ dinv,
                                                   float* __restrict__ part) {
  __shared__ float acc[CSZ];
  int tid = threadIdx.x;
  for (int j = tid; j < CSZ; j += 256) acc[j] = 0.f;
  __syncthreads();
  int chunk = blockIdx.x & (CKN - 1);
  int base = chunk * CSZ;
  const int4*   r4p = (const int4*)row + (blockIdx.x >> 2) * (ESL / 4);
  const int4*   c4p = (const int4*)col + (blockIdx.x >> 2) * (ESL / 4);
  const float4* a4p = (const float4*)ea + (blockIdx.x >> 2) * (ESL / 4);
  for (int i = tid; i < ESL / 4; i += 256) {
    int4   r4 = r4p[i];
    int4   c4 = c4p[i];
    float4 a4 = a4p[i];
    unsigned jx = (unsigned)(r4.x - base);
    unsigned jy = (unsigned)(r4.y - base);
    unsigned jz = (unsigned)(r4.z - base);
    unsigned jw = (unsigned)(r4.w - base);
    if (jx < CSZ) atomicAdd(&acc[jx], a4.x * dinv[c4.x]);
    if (jy < CSZ) atomicAdd(&acc[jy], a4.y * dinv[c4.y]);
    if (jz < CSZ) atomicAdd(&acc[jz], a4.z * dinv[c4.z]);
    if (jw < CSZ) atomicAdd(&acc[jw], a4.w * dinv[c4.w]);
  }
  __syncthreads();
  float* out = part + (size_t)blockIdx.x * CSZ;
  for (int j = tid; j < CSZ; j += 256) out[j] = acc[j];
}

// c[i] = dinv[i]^2 + dinv[i] * sum_p coefpart[p][i]
__global__ __launch_bounds__(256) void k_csum2(const float* __restrict__ part,
                                               const float* __restrict__ dinv,
                                               float* __restrict__ c) {
  int i = blockIdx.x * 256 + threadIdx.x;
  if (i >= NN) return;
  int chunk = i / CSZ, j = i - chunk * CSZ;
  const float* q = part + (size_t)chunk * CSZ + j;
  float s0 = 0.f, s1 = 0.f, s2 = 0.f, s3 = 0.f;
#pragma unroll
  for (int p = 0; p < PSL; p += 4) {
    s0 += q[(size_t)(p + 0) * (CKN * CSZ)];
    s1 += q[(size_t)(p + 1) * (CKN * CSZ)];
    s2 += q[(size_t)(p + 2) * (CKN * CSZ)];
    s3 += q[(size_t)(p + 3) * (CKN * CSZ)];
  }
  float di = dinv[i];
  c[i] = di * di + di * ((s0 + s1) + (s2 + s3));
}

// ---- fallback path (global-atomic version) if ws is too small ----
__global__ __launch_bounds__(256) void k_deg(const int* __restrict__ col,
                                             const float* __restrict__ ea,
                                             float* __restrict__ deg8) {
  int i = blockIdx.x * 256 + threadIdx.x;
  float* d = deg8 + (blockIdx.x & 7) * NP;
  if (i < EE / 4) {
    int4   c4 = ((const int4*)col)[i];
    float4 a4 = ((const float4*)ea)[i];
    atomicAdd(&d[c4.x], a4.x);
    atomicAdd(&d[c4.y], a4.y);
    atomicAdd(&d[c4.z], a4.z);
    atomicAdd(&d[c4.w], a4.w);
  }
}
__global__ __launch_bounds__(256) void k_dinv(const float* __restrict__ deg8,
                                              float* __restrict__ dinv) {
  int i = blockIdx.x * 256 + threadIdx.x;
  if (i < NN) {
    float s = 1.0f;
#pragma unroll
    for (int j = 0; j < NCOPY; ++j) s += deg8[j * NP + i];
    dinv[i] = rsqrtf(s);
  }
}
__global__ __launch_bounds__(256) void k_coef(const int* __restrict__ row,
                                              const int* __restrict__ col,
                                              const float* __restrict__ ea,
                                              const float* __restrict__ dinv,
                                              float* __restrict__ coef8) {
  int i = blockIdx.x * 256 + threadIdx.x;
  float* cf = coef8 + (blockIdx.x & 7) * NP;
  if (i < EE / 4) {
    int4   r4 = ((const int4*)row)[i];
    int4   c4 = ((const int4*)col)[i];
    float4 a4 = ((const float4*)ea)[i];
    atomicAdd(&cf[r4.x], a4.x * dinv[c4.x] * dinv[r4.x]);
    atomicAdd(&cf[r4.y], a4.y * dinv[c4.y] * dinv[r4.y]);
    atomicAdd(&cf[r4.z], a4.z * dinv[c4.z] * dinv[r4.z]);
    atomicAdd(&cf[r4.w], a4.w * dinv[c4.w] * dinv[r4.w]);
  }
}
__global__ __launch_bounds__(256) void k_csum(const float* __restrict__ coef8,
                                              const float* __restrict__ dinv,
                                              float* __restrict__ c) {
  int i = blockIdx.x * 256 + threadIdx.x;
  if (i < NN) {
    float di = dinv[i];
    float s = di * di;
#pragma unroll
    for (int j = 0; j < NCOPY; ++j) s += coef8[j * NP + i];
    c[i] = s;
  }
}

// v[l] += sum_n c[n]*relu(conv(x,w)+b)[l].
// conv4: thread = node (256B/wave coalesced), l-space SPLIT ACROSS BLOCKS:
// block (nb, g) computes l in [24g, 24g+24) for nodes nb*256..+255 from a
// 101-float register window.  R2 lesson: a 197-float window forced the
// compiler to interleave loads with FMAs (VGPR 168 < window size), exposing
// full memory latency at 0.77 waves/SIMD.  101 floats fits ~150 VGPR ->
// 3 waves/SIMD, grid 1372 blocks = 5488 waves, sched_barrier(0) pins all
// loads above compute (pattern proven in the 268us ancestor kernel).
// Traffic: x 1.37x (142MB, mostly L3-resident) + w 7x (45MB) ~= 190MB.
__global__ __launch_bounds__(256, 2) void k_conv4(const float* __restrict__ x,
                                                  const float* __restrict__ cw,
                                                  const float* __restrict__ cb,
                                                  const float* __restrict__ c,
                                                  float* __restrict__ v16) {
  __shared__ float vloc[LPB];
  int tid = threadIdx.x;
  if (tid < LPB) vloc[tid] = 0.f;
  __syncthreads();

  int nb = blockIdx.x % NB;
  int g  = blockIdx.x / NB;        // 0..6
  int n = nb * 256 + tid;
  int nc = n < NN ? n : NN - 1;    // clamp for safe loads; cn=0 kills contrib
  float cn = n < NN ? c[n] : 0.f;
  float bn = cb[nc];

  float w[KC];
  const float4* w4 = (const float4*)(cw + (size_t)nc * KC);
#pragma unroll
  for (int k = 0; k < KC / 4; ++k) {
    float4 t = w4[k];
    w[4 * k] = t.x; w[4 * k + 1] = t.y; w[4 * k + 2] = t.z; w[4 * k + 3] = t.w;
  }

  // register window: t in [72g, 72g+101); clamp pollutes only l >= 163
  const float* xp = x + nc;
  float xs[WIN];
#pragma unroll
  for (int j = 0; j < WIN; ++j) {
    int t = 72 * g + j;
    t = t < TT ? t : TT - 1;
    xs[j] = xp[(size_t)t * NN];
  }
  __builtin_amdgcn_sched_barrier(0);   // loads stay ABOVE, compute BELOW

  int lane = tid & 63;
#pragma unroll
  for (int cc = 0; cc < 3; ++cc) {
    float accv[8];
#pragma unroll
    for (int u = 0; u < 8; ++u) {
      float h = 0.f;
#pragma unroll
      for (int k = 0; k < KC; ++k) h += xs[24 * cc + 3 * u + k] * w[k];
      h += bn;
      h = h > 0.f ? h : 0.f;
      accv[u] = cn * h;
    }
#pragma unroll
    for (int u = 0; u < 8; ++u) {
      float val = accv[u];
      val += __shfl_xor(val, 1, 64);
      val += __shfl_xor(val, 2, 64);
      val += __shfl_xor(val, 4, 64);
      val += __shfl_xor(val, 8, 64);
      val += __shfl_xor(val, 16, 64);
      val += __shfl_xor(val, 32, 64);
      if (lane == 0) atomicAdd(&vloc[8 * cc + u], val);
    }
  }
  __syncthreads();
  float* vdst = v16 + (blockIdx.x & (VS - 1)) * VSTR;
  if (tid < LPB) {
    int l = LPB * g + tid;
    if (l < LL) atomicAdd(&vdst[l], vloc[tid]);
  }
}

// out[h] = (sum_l (sum_j v16[j][l]) * W[l][h]) / N + gcn_b[h]
__global__ __launch_bounds__(128) void k_out(const float* __restrict__ v16,
                                             const float* __restrict__ W,
                                             const float* __restrict__ b,
                                             float* __restrict__ out) {
  __shared__ float vs[LL];
  int h = threadIdx.x;
  for (int l = h; l < LL; l += 128) {
    float s = 0.f;
#pragma unroll
    for (int j = 0; j < VS; ++j) s += v16[j * VSTR + l];
    vs[l] = s;
  }
  __syncthreads();
  float s = 0.f;
  for (int l = 0; l < LL; ++l) s += vs[l] * W[l * HH + h];
  out[h] = s * (1.0f / NN) + b[h];
}

extern "C" void kernel_launch(void* const* d_in, const int* in_sizes, int n_in,
                              void* d_out, int out_size, void* d_ws, size_t ws_size,
                              hipStream_t stream) {
  const float* x  = (const float*)d_in[0];
  const int*   ei = (const int*)d_in[1];
  const float* ea = (const float*)d_in[2];
  const float* cw = (const float*)d_in[3];
  const float* cb = (const float*)d_in[4];
  const float* gW = (const float*)d_in[5];
  const float* gb = (const float*)d_in[6];
  float* out = (float*)d_out;

  const int* row = ei;
  const int* col = ei + EE;
  float* ws = (float*)d_ws;

  size_t need_new = ((size_t)GSC * CSZ + VS * VSTR + 2 * NP) * sizeof(float);
  if (ws_size >= need_new) {
    float* part = ws;                          // GSC*CSZ floats (reused deg->coef)
    float* v16  = ws + (size_t)GSC * CSZ;      // VS*VSTR floats
    float* dinv = v16 + VS * VSTR;             // NP floats
    float* c    = dinv + NP;                   // NP floats
    hipMemsetAsync(v16, 0, VS * VSTR * sizeof(float), stream);
    k_deg_part <<<GSC, 256, 0, stream>>>(col, ea, part);
    k_dinv2    <<<NB, 256, 0, stream>>>(part, dinv);
    k_coef_part<<<GSC, 256, 0, stream>>>(row, col, ea, dinv, part);
    k_csum2    <<<NB, 256, 0, stream>>>(part, dinv, c);
    k_conv4    <<<NB * GRP, 256, 0, stream>>>(x, cw, cb, c, v16);
    k_out      <<<1, 128, 0, stream>>>(v16, gW, gb, out);
  } else {
    float* deg8  = ws;
    float* coef8 = ws + NCOPY * NP;
    float* v16   = ws + 2 * NCOPY * NP;
    float* dinv  = ws + 2 * NCOPY * NP + VS * VSTR;
    float* c     = dinv + NP;
    hipMemsetAsync(deg8, 0, (2 * NCOPY * NP + VS * VSTR) * sizeof(float), stream);
    int egrid = (EE / 4 + 255) / 256;
    k_deg  <<<egrid, 256, 0, stream>>>(col, ea, deg8);
    k_dinv <<<NB, 256, 0, stream>>>(deg8, dinv);
    k_coef <<<egrid, 256, 0, stream>>>(row, col, ea, dinv, coef8);
    k_csum <<<NB, 256, 0, stream>>>(coef8, dinv, c);
    k_conv4<<<NB * GRP, 256, 0, stream>>>(x, cw, cb, c, v16);
    k_out  <<<1, 128, 0, stream>>>(v16, gW, gb, out);
  }
}